// Round 21
// baseline (551.732 us; speedup 1.0000x reference)
//
#include <hip/hip_runtime.h>
#include <hip/hip_bf16.h>
#include <math.h>

#define F_IN   128
#define HID    128
#define NLAYER 3
#define NCLS   40
#define DCAT   512   // F_IN + NLAYER*HID
#define OOUT   64    // padded out-layer cols

typedef short s16x8 __attribute__((ext_vector_type(8)));
typedef unsigned short u16x8 __attribute__((ext_vector_type(8)));
typedef unsigned short u16x4 __attribute__((ext_vector_type(4)));
typedef unsigned short u16x2 __attribute__((ext_vector_type(2)));
typedef float f32x4 __attribute__((ext_vector_type(4)));
typedef unsigned long long u64x2 __attribute__((ext_vector_type(2)));

// ---------------- device helpers ----------------

static __device__ __forceinline__ float silu_f(float x) {
    return x / (1.f + __expf(-x));
}

static __device__ __forceinline__ unsigned short f2bf_rn(float f) {
    union { __hip_bfloat16 h; unsigned short u; } cv;
    cv.h = __float2bfloat16(f);
    return cv.u;
}

static __device__ __forceinline__ float bf2f(unsigned short u) {
    return __uint_as_float((unsigned)u << 16);
}

// LDS-only barrier: drain ds ops (lgkmcnt) but leave global loads in flight.
static __device__ __forceinline__ void lds_barrier() {
    asm volatile("s_waitcnt lgkmcnt(0)" ::: "memory");
    __builtin_amdgcn_s_barrier();
}

// ---------------- graph preprocessing ----------------
// deg[] is zero-initialized by memset; true degree = deg[i] + 1 (self-loop).

__global__ __launch_bounds__(256) void deg_count_kernel(const int* __restrict__ dst, int E, int* deg) {
    for (int i = blockIdx.x * blockDim.x + threadIdx.x; i < E; i += gridDim.x * blockDim.x)
        atomicAdd(&deg[dst[i]], 1);
}

// hierarchical scan: 1 elem/thread, 256/block
__global__ __launch_bounds__(256) void scan_reduce_kernel(const int* __restrict__ deg, int* __restrict__ bsum, int N) {
    __shared__ int sh[256];
    int t = threadIdx.x;
    int e = blockIdx.x * 256 + t;
    sh[t] = (e < N) ? deg[e] + 1 : 0;
    __syncthreads();
#pragma unroll
    for (int off = 128; off > 0; off >>= 1) {
        if (t < off) sh[t] += sh[t + off];
        __syncthreads();
    }
    if (t == 0) bsum[blockIdx.x] = sh[0];
}

__global__ __launch_bounds__(256) void scan_top_kernel(const int* __restrict__ bsum, int* __restrict__ bbase, int nsb) {
    __shared__ int sh[256];
    int t = threadIdx.x;
    int chunk = (nsb + 255) >> 8;
    int begin = t * chunk;
    int end = begin + chunk; if (end > nsb) end = nsb;
    int s = 0;
    for (int i = begin; i < end; ++i) s += bsum[i];
    sh[t] = s;
    __syncthreads();
#pragma unroll
    for (int off = 1; off < 256; off <<= 1) {
        int v = 0;
        if (t >= off) v = sh[t - off];
        __syncthreads();
        if (t >= off) sh[t] += v;
        __syncthreads();
    }
    int run = (t == 0) ? 0 : sh[t - 1];
    for (int i = begin; i < end; ++i) {
        bbase[i] = run;
        run += bsum[i];
    }
}

// also computes dinv = rsqrt(degree) inline
__global__ __launch_bounds__(256) void scan_write_kernel(const int* __restrict__ deg,
                                                         const int* __restrict__ bbase,
                                                         int* __restrict__ offs, int* __restrict__ cursor,
                                                         float* __restrict__ dinv, int N) {
    __shared__ int sh[256];
    int t = threadIdx.x;
    int e = blockIdx.x * 256 + t;
    int d = (e < N) ? deg[e] + 1 : 0;
    sh[t] = d;
    __syncthreads();
#pragma unroll
    for (int off = 1; off < 256; off <<= 1) {
        int v = 0;
        if (t >= off) v = sh[t - off];
        __syncthreads();
        if (t >= off) sh[t] += v;
        __syncthreads();
    }
    int incl = sh[t] + bbase[blockIdx.x];
    int excl = incl - d;
    if (e < N) {
        offs[e] = excl;
        cursor[e] = excl;
        dinv[e] = rsqrtf((float)d);
        if (e == N - 1) offs[N] = incl;
    }
}

__global__ __launch_bounds__(256) void fill_kernel(const int* __restrict__ src, const int* __restrict__ dst,
                                                   int E, int N, int* cursor, int* __restrict__ csr) {
    int total = E + N;
    for (int i = blockIdx.x * blockDim.x + threadIdx.x; i < total; i += gridDim.x * blockDim.x) {
        if (i < E) {
            int d = dst[i];
            int p = atomicAdd(&cursor[d], 1);
            csr[p] = src[i];
        } else {
            int n = i - E;
            int p = atomicAdd(&cursor[n], 1);
            csr[p] = n;
        }
    }
}

// ---------------- weight packing (bf16, MFMA-fragment order), merged ---------
#define TC_PACK (NLAYER * 9 * 4 * 8 * 64 * 8)
#define TO_PACK (36 * 4 * 4 * 64 * 8)
__global__ __launch_bounds__(256) void pack_all_kernel(const float* __restrict__ cbw,
                                                       const float* __restrict__ csw,
                                                       const float* __restrict__ csc,
                                                       const float* __restrict__ obw,
                                                       const float* __restrict__ osw,
                                                       const float* __restrict__ osc,
                                                       unsigned short* __restrict__ wpkc,
                                                       unsigned short* __restrict__ wpko,
                                                       float* __restrict__ scA, float* __restrict__ shA) {
    int gid0 = blockIdx.x * blockDim.x + threadIdx.x;
    if (gid0 < 128) { scA[gid0] = 1.f; shA[gid0] = 0.f; }
    int total = TC_PACK + TO_PACK;
    for (int idx = gid0; idx < total; idx += gridDim.x * blockDim.x) {
        if (idx < TC_PACK) {
            int e    = idx & 7;
            int lane = (idx >> 3) & 63;
            int cf   = (idx >> 9) & 7;
            int kk   = (idx >> 12) & 3;
            int cc   = (idx >> 14) % 9;
            int l    = idx / (9 << 14);
            int o = cf * 16 + (lane & 15);
            int k = kk * 32 + ((lane >> 4) << 3) + e;
            float v;
            if (cc == 8) {
                v = cbw[(l * 128 + o) * 128 + k];
            } else {
                int f = cc * 16 + (k >> 3);
                int j = k & 7;
                int base = (l * 128 + o) * 128 + f;
                v = csw[base * 8 + j] * csc[base];
            }
            wpkc[idx] = f2bf_rn(v);
        } else {
            int ix = idx - TC_PACK;
            int e    = ix & 7;
            int lane = (ix >> 3) & 63;
            int cf   = (ix >> 9) & 3;
            int kk   = (ix >> 11) & 3;
            int gcc  = ix >> 13;
            int g = gcc / 9, cc = gcc % 9;
            int o = cf * 16 + (lane & 15);
            int k = kk * 32 + ((lane >> 4) << 3) + e;
            float v = 0.f;
            if (o < NCLS) {
                if (cc == 8) {
                    int f = g * 128 + k;
                    v = obw[o * DCAT + f];
                } else {
                    int f = g * 128 + cc * 16 + (k >> 3);
                    int j = k & 7;
                    int base = o * DCAT + f;
                    v = osw[base * 8 + j] * osc[base];
                }
            }
            wpko[ix] = f2bf_rn(v);
        }
    }
}

// ---------------- fused KAN GEMM + out-layer partial (bf16 MFMA 16x16x32) ----
// Block: 512 threads = 8 waves (2 per SIMD) so each SIMD interleaves two
// waves: one wave's MFMA/LDS/load latency hides under the other's phi-VALU.
// Tile 64 nodes; column split 8-way: wave w owns conv frag w (16 cols);
// waves 0..2 additionally own out frags 0..2 (frag 3 = all padding, skipped).
// phi double-buffered in LDS, one lgkm-only barrier/chunk; W prefetched one
// chunk ahead; x two chunks ahead; silu kept in registers, written as chunk 8.
template<bool CONV, bool INIT>
__global__ __launch_bounds__(512, 2) void kan_fused_kernel(
    const float* __restrict__ xin, int xstride, int in_off,
    const float* __restrict__ scA, const float* __restrict__ shA,
    const unsigned short* __restrict__ wconv,
    const unsigned short* __restrict__ wout,
    unsigned short* __restrict__ htmp,
    const float* __restrict__ dinv,
    float* __restrict__ out_acc, int N) {

    __shared__ __align__(16) char lds_phi0[16384];
    __shared__ __align__(16) char lds_phi1[16384];

    const int tid = threadIdx.x;
    const int lane = tid & 63;
    const int wave = tid >> 6;       // 0..7
    const int l15 = lane & 15, lg = lane >> 4;
    const int nblk = blockIdx.x * 64;

    const float g0 = -1.f - 3.f * 0.4f;
    const float invh = 1.f / 0.4f;

    const int fg2 = tid & 7;         // 2 features per thread
    const int n0 = tid >> 3;         // 0..63

    const bool has_out = (wave < 3); // out frag 3 is all padding -> skipped

    f32x4 accc[4];   // conv frag `wave` x 4 row tiles
    f32x4 acco[4];   // out frag `wave` (waves 0..2) x 4 row tiles
    if (CONV) {
#pragma unroll
        for (int r = 0; r < 4; ++r) accc[r] = (f32x4)0.f;
    }
#pragma unroll
    for (int r = 0; r < 4; ++r) acco[r] = (f32x4)0.f;

    // double-buffered x/affine (2 chunks ahead), 2 feats/thread
    float2 xqb[2], scb[2], shb[2];
    auto ldx = [&](int cc, int slot) {
        int f0 = in_off + cc * 16 + fg2 * 2;   // in_off==0 when xstride==F_IN
        scb[slot] = *(const float2*)(scA + f0);
        shb[slot] = *(const float2*)(shA + f0);
        int gn = nblk + n0;
        xqb[slot] = (gn < N) ? *(const float2*)(xin + (size_t)gn * xstride + f0)
                             : (float2){0.f, 0.f};
    };

    // W fragments for one chunk, prefetched a chunk ahead (1 conv + <=1 out frag per wave)
    s16x8 wc_reg[4];
    s16x8 wo_reg[4];
    auto loadW = [&](int cc) {
        if (CONV) {
            const unsigned short* wcb = wconv + (size_t)cc * 16384;
#pragma unroll
            for (int kk = 0; kk < 4; ++kk)
                wc_reg[kk] = *(const s16x8*)(wcb + (((size_t)kk * 8 + wave) * 64 + lane) * 8);
        }
        if (has_out) {
            const unsigned short* wob = wout + (size_t)cc * 8192;
#pragma unroll
            for (int kk = 0; kk < 4; ++kk)
                wo_reg[kk] = *(const s16x8*)(wob + (((size_t)kk * 4 + wave) * 64 + lane) * 8);
        }
    };

    // silu values for chunks 0..7 (2 per thread), written as chunk 8
    u16x2 sreg[8];

    // per-feature spline rows as 128-bit {lo,hi}
    u64x2 pcur[2];
    auto phi_compute = [&](int ccc, int slot) {
        float xi[2] = {xqb[slot].x, xqb[slot].y};
        float scr[2] = {scb[slot].x, scb[slot].y};
        float shr[2] = {shb[slot].x, shb[slot].y};
        u16x2 sv;
#pragma unroll
        for (int fl = 0; fl < 2; ++fl) {
            float y = fmaf(xi[fl], scr[fl], shr[fl]);
            sv[fl] = f2bf_rn(silu_f(y));
            float t = (y - g0) * invh;
            float cfl = floorf(t);
            int c = (int)cfl;
            c = c < -20 ? -20 : (c > 20 ? 20 : c);   // keep pos arithmetic safe
            float u = t - cfl;
            float um = 1.f - u;
            float u2 = u * u;
            float um2 = um * um;
            float w0 = um2 * um * (1.f / 6.f);
            float w3 = u2 * u * (1.f / 6.f);
            float w1 = fmaf(fmaf(0.5f, u, -1.f), u2, 2.f / 3.f);
            float w2 = fmaf(fmaf(-0.5f, u, 0.5f), u2, fmaf(0.5f, u, 1.f / 6.f));
            unsigned long long W = (unsigned long long)f2bf_rn(w0)
                                 | ((unsigned long long)f2bf_rn(w1) << 16)
                                 | ((unsigned long long)f2bf_rn(w2) << 32)
                                 | ((unsigned long long)f2bf_rn(w3) << 48);
            int pos = (c - 3) * 16;
            unsigned long long lo = (pos >= 0) ? (W << (pos & 63)) : (W >> ((-pos) & 63));
            lo = (pos >= 64 || pos <= -64) ? 0ull : lo;
            int ph = pos - 64;
            unsigned long long hi = (ph >= 0) ? (W << (ph & 63)) : (W >> ((-ph) & 63));
            hi = (ph >= 64 || ph <= -64) ? 0ull : hi;
            u64x2 v; v.x = lo; v.y = hi;
            pcur[fl] = v;
        }
        sreg[ccc] = sv;
    };

    auto write_phi = [&](char* buf) {
        int swz = (n0 & 7) << 4;
#pragma unroll
        for (int i = 0; i < 2; ++i) {
            int byte = n0 * 256 + ((fg2 * 32 + i * 16) ^ swz);
            *(u64x2*)(buf + byte) = pcur[i];
        }
    };

    auto write_silu = [&](char* buf) {
        int swz = (n0 & 7) << 4;
#pragma unroll
        for (int ccc = 0; ccc < 8; ++ccc) {
            int byte = n0 * 256 + (((ccc * 16 + fg2 * 2) * 2) ^ swz);
            *(u16x2*)(buf + byte) = sreg[ccc];
        }
    };

    auto mfma_phase = [&](const char* buf) {
#pragma unroll
        for (int kk = 0; kk < 4; ++kk) {
            const int kb = kk * 64 + lg * 16;
            s16x8 af[4];
#pragma unroll
            for (int r = 0; r < 4; ++r) {
                int n = r * 16 + l15;
                af[r] = *(const s16x8*)(buf + n * 256 + (kb ^ ((n & 7) << 4)));
            }
            if (CONV) {
#pragma unroll
                for (int r = 0; r < 4; ++r)
                    accc[r] = __builtin_amdgcn_mfma_f32_16x16x32_bf16(af[r], wc_reg[kk], accc[r], 0, 0, 0);
            }
            if (has_out) {
#pragma unroll
                for (int r = 0; r < 4; ++r)
                    acco[r] = __builtin_amdgcn_mfma_f32_16x16x32_bf16(af[r], wo_reg[kk], acco[r], 0, 0, 0);
            }
        }
    };

    // ---- prologue: chunk 0 phi + W(0) + x(1) prefetch ----
    ldx(0, 0);
    phi_compute(0, 0);
    ldx(1, 1);
    loadW(0);
    write_phi(lds_phi0);
    __syncthreads();   // full drain once

    // ---- pipelined chunk loop (fully unrolled; one lgkm-barrier per chunk) ----
#pragma unroll
    for (int cc = 0; cc < 9; ++cc) {
        char* cur = (cc & 1) ? lds_phi1 : lds_phi0;
        char* nxt = (cc & 1) ? lds_phi0 : lds_phi1;
        if (cc < 7) ldx(cc + 2, cc & 1);       // issue x early (covered by MFMA+phi)
        mfma_phase(cur);
        if (cc < 8) loadW(cc + 1);             // prefetch next chunk's W
        if (cc < 7) {
            phi_compute(cc + 1, (cc + 1) & 1); // overlaps W-load latency
            write_phi(nxt);
        }
        if (cc == 7) write_silu(nxt);          // chunk 8 = silu from registers
        if (cc < 8) lds_barrier();             // ds-drain only; globals stay in flight
    }

    // epilogue: row = r*16 + lg*4 + q; conv col = wave*16 + l15; out col = wave*16 + l15
#pragma unroll
    for (int r = 0; r < 4; ++r) {
        int nb = nblk + r * 16 + lg * 4;
        if (CONV) {
            int o = wave * 16 + l15;
#pragma unroll
            for (int q = 0; q < 4; ++q) {
                int n = nb + q;
                if (n < N) htmp[(size_t)n * HID + o] = f2bf_rn(accc[r][q] * dinv[n]);
            }
        }
        if (has_out) {
            int o = wave * 16 + l15;
            if (o < NCLS) {
#pragma unroll
                for (int q = 0; q < 4; ++q) {
                    int n = nb + q;
                    if (n < N) {
                        size_t a = (size_t)n * OOUT + o;
                        float v = acco[r][q];
                        if (!INIT) v += out_acc[a];
                        out_acc[a] = v;
                    }
                }
            }
        }
    }
}

// ---------------- aggregation (wave per node, 4 rows per memory instr) -------
__global__ __launch_bounds__(256) void agg_kernel(const unsigned short* __restrict__ h,
                                                  const float* __restrict__ dinv,
                                                  const int* __restrict__ offs,
                                                  const int* __restrict__ csr,
                                                  const float* __restrict__ bias,
                                                  float* __restrict__ xc, int out_off, int N) {
    int n = blockIdx.x * 4 + (threadIdx.x >> 6);
    if (n >= N) return;
    int lane = threadIdx.x & 63;
    int eg = lane >> 4;        // 0..3
    int cg = lane & 15;        // col group: cols cg*8..cg*8+7
    int s = offs[n], e = offs[n + 1];

    float acc[4][8];
#pragma unroll
    for (int a = 0; a < 4; ++a)
#pragma unroll
        for (int k = 0; k < 8; ++k) acc[a][k] = 0.f;

    for (int base = s; base < e; base += 64) {
        int cnt = e - base; if (cnt > 64) cnt = 64;
        int ci = base + lane;
        int cv = (ci < e) ? csr[ci] : 0;

#pragma unroll
        for (int j = 0; j < 4; ++j) {
            int ei = j * 4 + eg;
            int v = __shfl(cv, ei);
            if (ei < cnt) {
                u16x8 hv = *(const u16x8*)(h + (size_t)v * HID + cg * 8);
#pragma unroll
                for (int k = 0; k < 8; ++k) acc[j][k] += bf2f(hv[k]);
            }
        }
        int nj = (cnt + 3) >> 2;
        for (int j = 4; j < nj; ++j) {
            int ei = j * 4 + eg;
            int v = __shfl(cv, ei);
            if (ei < cnt) {
                u16x8 hv = *(const u16x8*)(h + (size_t)v * HID + cg * 8);
#pragma unroll
                for (int k = 0; k < 8; ++k) acc[j & 3][k] += bf2f(hv[k]);
            }
        }
    }

    float tot[8];
#pragma unroll
    for (int k = 0; k < 8; ++k)
        tot[k] = (acc[0][k] + acc[1][k]) + (acc[2][k] + acc[3][k]);
#pragma unroll
    for (int k = 0; k < 8; ++k) {
        tot[k] += __shfl_xor(tot[k], 16);
        tot[k] += __shfl_xor(tot[k], 32);
    }
    if (eg == 0) {
        float dn = dinv[n];
        float4 b0 = *(const float4*)(bias + cg * 8);
        float4 b1 = *(const float4*)(bias + cg * 8 + 4);
        float4 o0 = {fmaf(tot[0], dn, b0.x), fmaf(tot[1], dn, b0.y),
                     fmaf(tot[2], dn, b0.z), fmaf(tot[3], dn, b0.w)};
        float4 o1 = {fmaf(tot[4], dn, b1.x), fmaf(tot[5], dn, b1.y),
                     fmaf(tot[6], dn, b1.z), fmaf(tot[7], dn, b1.w)};
        float* dst = xc + (size_t)n * DCAT + out_off + cg * 8;
        *(float4*)dst = o0;
        *(float4*)(dst + 4) = o1;
    }
}

// ---------------- batchnorm stats + fused affine (last-block ticket) ---------
__global__ __launch_bounds__(128) void bn_stats_kernel(const float* __restrict__ xc, int off, int N,
                                                       float* __restrict__ bnsum, float* __restrict__ bnsq,
                                                       const float* __restrict__ gamma,
                                                       const float* __restrict__ beta,
                                                       float* scA, float* shA, int seg_off, float invN,
                                                       int* __restrict__ counter) {
    __shared__ int last;
    int f = threadIdx.x;
    float s = 0.f, q = 0.f;
    for (int n = blockIdx.x; n < N; n += gridDim.x) {
        float v = xc[(size_t)n * DCAT + off + f];
        s += v;
        q += v * v;
    }
    atomicAdd(&bnsum[f], s);
    atomicAdd(&bnsq[f], q);
    __threadfence();
    __syncthreads();
    if (f == 0) {
        int t = atomicAdd(counter, 1);
        last = (t == (int)gridDim.x - 1);
    }
    __syncthreads();
    if (last) {
        float mu = bnsum[f] * invN;
        float var = bnsq[f] * invN - mu * mu;
        float rs = rsqrtf(var + 1e-5f);
        float sc = gamma[f] * rs;
        scA[seg_off + f] = sc;
        shA[seg_off + f] = fmaf(-mu, sc, beta[f]);
        if (f == 0) *counter = 0;   // self-reset (replay-safe)
    }
}

// ---------------- log_softmax (thread per node; reads out_acc ld=64) ---------
__global__ __launch_bounds__(256) void logsoftmax_kernel(const float* __restrict__ oacc,
                                                         float* __restrict__ out, int N) {
    for (int n = blockIdx.x * blockDim.x + threadIdx.x; n < N; n += gridDim.x * blockDim.x) {
        const float* row = oacc + (size_t)n * OOUT;
        float m = -1e30f;
#pragma unroll
        for (int j = 0; j < NCLS; ++j) m = fmaxf(m, row[j]);
        float s = 0.f;
#pragma unroll
        for (int j = 0; j < NCLS; ++j) s += __expf(row[j] - m);
        float lse = m + __logf(s);
        float* orow = out + (size_t)n * NCLS;
#pragma unroll
        for (int j = 0; j < NCLS; ++j) orow[j] = row[j] - lse;
    }
}

// ---------------- launch ----------------

extern "C" void kernel_launch(void* const* d_in, const int* in_sizes, int n_in,
                              void* d_out, int out_size, void* d_ws, size_t ws_size,
                              hipStream_t stream) {
    const float* x            = (const float*)d_in[0];
    const int*   eidx         = (const int*)d_in[1];
    const float* conv_base_w  = (const float*)d_in[3];
    const float* conv_spline_w= (const float*)d_in[4];
    const float* conv_scaler  = (const float*)d_in[5];
    const float* conv_bias    = (const float*)d_in[6];
    const float* bn_gamma     = (const float*)d_in[7];
    const float* bn_beta      = (const float*)d_in[8];
    const float* out_base_w   = (const float*)d_in[10];
    const float* out_spline_w = (const float*)d_in[11];
    const float* out_scaler   = (const float*)d_in[12];
    float* out = (float*)d_out;

    int N = in_sizes[0] / F_IN;
    int E = in_sizes[1] / 2;
    const int* esrc = eidx;
    const int* edst = eidx + E;

    int blocks = (N + 63) / 64;
    int npad = blocks * 64;
    int nsb = (N + 255) / 256;

    char* p = (char*)d_ws;
    auto carve = [&](size_t bytes) {
        char* r = p;
        p += (bytes + 255) & ~(size_t)255;
        return r;
    };
    float* xc   = (float*)carve((size_t)N * DCAT * 4);
    unsigned short* htmp = (unsigned short*)carve((size_t)npad * HID * 2);
    float* oacc = (float*)carve((size_t)npad * OOUT * 4);
    float* dinv = (float*)carve((size_t)N * 4);
    float* bn   = (float*)carve((size_t)NLAYER * 2 * HID * 4 + 256);  // + ticket counter
    int* counter = (int*)(bn + NLAYER * 2 * HID);
    float* scA  = (float*)carve((size_t)DCAT * 4);
    float* shA  = (float*)carve((size_t)DCAT * 4);
    unsigned short* wpkc = (unsigned short*)carve((size_t)NLAYER * 9 * 128 * 128 * 2);
    unsigned short* wpko = (unsigned short*)carve((size_t)36 * 64 * 128 * 2);
    int* deg    = (int*)carve((size_t)N * 4);
    int* offs   = (int*)carve((size_t)(N + 1) * 4);
    int* cursor = (int*)carve((size_t)(N + 1) * 4);
    int* bsum   = (int*)carve((size_t)nsb * 4);
    int* bbase  = (int*)carve((size_t)nsb * 4);
    int* csr    = (int*)carve((size_t)(E + N) * 4);

    hipMemsetAsync(bn, 0, NLAYER * 2 * HID * 4 + 256, stream);
    hipMemsetAsync(deg, 0, (size_t)N * 4, stream);

    // graph preprocessing
    deg_count_kernel<<<1024, 256, 0, stream>>>(edst, E, deg);
    scan_reduce_kernel<<<nsb, 256, 0, stream>>>(deg, bsum, N);
    scan_top_kernel<<<1, 256, 0, stream>>>(bsum, bbase, nsb);
    scan_write_kernel<<<nsb, 256, 0, stream>>>(deg, bbase, offs, cursor, dinv, N);
    fill_kernel<<<1024, 256, 0, stream>>>(esrc, edst, E, N, cursor, csr);

    // weight packing + affine seg-0 init (merged)
    pack_all_kernel<<<1024, 256, 0, stream>>>(conv_base_w, conv_spline_w, conv_scaler,
                                              out_base_w, out_spline_w, out_scaler,
                                              wpkc, wpko, scA, shA);

    float invN = 1.f / (float)N;
    for (int l = 0; l < NLAYER; ++l) {
        int in_off = l * HID;
        int out_off = (l + 1) * HID;
        const unsigned short* wl = wpkc + (size_t)l * 9 * 16384;
        const unsigned short* wo = wpko + (size_t)l * 9 * 8192;
        if (l == 0)
            kan_fused_kernel<true, true><<<blocks, 512, 0, stream>>>(
                x, F_IN, 0, scA, shA, wl, wo, htmp, dinv, oacc, N);
        else
            kan_fused_kernel<true, false><<<blocks, 512, 0, stream>>>(
                xc, DCAT, in_off, scA, shA, wl, wo, htmp, dinv, oacc, N);
        agg_kernel<<<(N + 3) / 4, 256, 0, stream>>>(htmp, dinv, offs, csr, conv_bias + l * HID, xc, out_off, N);
        float* bnsum = bn + l * 2 * HID;
        float* bnsq  = bnsum + HID;
        bn_stats_kernel<<<256, 128, 0, stream>>>(xc, out_off, N, bnsum, bnsq,
                                                 bn_gamma + l * HID, bn_beta + l * HID,
                                                 scA, shA, out_off, invN, counter);
    }

    // segment 3 (final BN output) -> out partial
    kan_fused_kernel<false, false><<<blocks, 512, 0, stream>>>(
        xc, DCAT, 384, scA, shA, nullptr, wpko + (size_t)3 * 9 * 8192, htmp, dinv, oacc, N);

    logsoftmax_kernel<<<(N + 255) / 256, 256, 0, stream>>>(oacc, out, N);
}

// Round 22
// 511.612 us; speedup vs baseline: 1.0784x; 1.0784x over previous
//
#include <hip/hip_runtime.h>
#include <hip/hip_bf16.h>
#include <math.h>

#define F_IN   128
#define HID    128
#define NLAYER 3
#define NCLS   40
#define DCAT   512   // F_IN + NLAYER*HID
#define OOUT   64    // padded out-layer cols

typedef short s16x8 __attribute__((ext_vector_type(8)));
typedef unsigned short u16x8 __attribute__((ext_vector_type(8)));
typedef unsigned short u16x4 __attribute__((ext_vector_type(4)));
typedef float f32x4 __attribute__((ext_vector_type(4)));
typedef unsigned long long u64x2 __attribute__((ext_vector_type(2)));

// ---------------- device helpers ----------------

static __device__ __forceinline__ float silu_f(float x) {
    return x / (1.f + __expf(-x));
}

static __device__ __forceinline__ unsigned short f2bf_rn(float f) {
    union { __hip_bfloat16 h; unsigned short u; } cv;
    cv.h = __float2bfloat16(f);
    return cv.u;
}

static __device__ __forceinline__ float bf2f(unsigned short u) {
    return __uint_as_float((unsigned)u << 16);
}

// LDS-only barrier: drain ds ops (lgkmcnt) but leave global loads in flight.
static __device__ __forceinline__ void lds_barrier() {
    asm volatile("s_waitcnt lgkmcnt(0)" ::: "memory");
    __builtin_amdgcn_s_barrier();
}

// ---------------- graph preprocessing ----------------

__global__ __launch_bounds__(256) void deg_init_kernel(int* deg, int N) {
    for (int i = blockIdx.x * blockDim.x + threadIdx.x; i < N; i += gridDim.x * blockDim.x)
        deg[i] = 1;  // self-loop
}

__global__ __launch_bounds__(256) void deg_count_kernel(const int* __restrict__ dst, int E, int* deg) {
    for (int i = blockIdx.x * blockDim.x + threadIdx.x; i < E; i += gridDim.x * blockDim.x)
        atomicAdd(&deg[dst[i]], 1);
}

__global__ __launch_bounds__(256) void dinv_kernel(const int* __restrict__ deg, float* dinv, int N) {
    for (int i = blockIdx.x * blockDim.x + threadIdx.x; i < N; i += gridDim.x * blockDim.x)
        dinv[i] = rsqrtf((float)deg[i]);
}

// hierarchical scan: 1 elem/thread, 256/block
__global__ __launch_bounds__(256) void scan_reduce_kernel(const int* __restrict__ deg, int* __restrict__ bsum, int N) {
    __shared__ int sh[256];
    int t = threadIdx.x;
    int e = blockIdx.x * 256 + t;
    sh[t] = (e < N) ? deg[e] : 0;
    __syncthreads();
#pragma unroll
    for (int off = 128; off > 0; off >>= 1) {
        if (t < off) sh[t] += sh[t + off];
        __syncthreads();
    }
    if (t == 0) bsum[blockIdx.x] = sh[0];
}

__global__ __launch_bounds__(256) void scan_top_kernel(const int* __restrict__ bsum, int* __restrict__ bbase, int nsb) {
    __shared__ int sh[256];
    int t = threadIdx.x;
    int chunk = (nsb + 255) >> 8;
    int begin = t * chunk;
    int end = begin + chunk; if (end > nsb) end = nsb;
    int s = 0;
    for (int i = begin; i < end; ++i) s += bsum[i];
    sh[t] = s;
    __syncthreads();
#pragma unroll
    for (int off = 1; off < 256; off <<= 1) {
        int v = 0;
        if (t >= off) v = sh[t - off];
        __syncthreads();
        if (t >= off) sh[t] += v;
        __syncthreads();
    }
    int run = (t == 0) ? 0 : sh[t - 1];
    for (int i = begin; i < end; ++i) {
        bbase[i] = run;
        run += bsum[i];
    }
}

__global__ __launch_bounds__(256) void scan_write_kernel(const int* __restrict__ deg,
                                                         const int* __restrict__ bbase,
                                                         int* __restrict__ offs, int* __restrict__ cursor, int N) {
    __shared__ int sh[256];
    int t = threadIdx.x;
    int e = blockIdx.x * 256 + t;
    int d = (e < N) ? deg[e] : 0;
    sh[t] = d;
    __syncthreads();
#pragma unroll
    for (int off = 1; off < 256; off <<= 1) {
        int v = 0;
        if (t >= off) v = sh[t - off];
        __syncthreads();
        if (t >= off) sh[t] += v;
        __syncthreads();
    }
    int incl = sh[t] + bbase[blockIdx.x];
    int excl = incl - d;
    if (e < N) {
        offs[e] = excl;
        cursor[e] = excl;
        if (e == N - 1) offs[N] = incl;
    }
}

__global__ __launch_bounds__(256) void fill_kernel(const int* __restrict__ src, const int* __restrict__ dst,
                                                   int E, int N, int* cursor, int* __restrict__ csr) {
    int total = E + N;
    for (int i = blockIdx.x * blockDim.x + threadIdx.x; i < total; i += gridDim.x * blockDim.x) {
        if (i < E) {
            int d = dst[i];
            int p = atomicAdd(&cursor[d], 1);
            csr[p] = src[i];
        } else {
            int n = i - E;
            int p = atomicAdd(&cursor[n], 1);
            csr[p] = n;
        }
    }
}

// ---------------- weight packing (bf16, MFMA-fragment order) -----------------
// B-fragment for 16x16x32: lane holds W[o = cf*16 + (lane&15)][k = kk*32 + (lane>>4)*8 + e].
// conv: [l][cc(9)][kk(4)][cf(8)][lane(64)][e(8)]
__global__ __launch_bounds__(256) void pack_conv_mfma(const float* __restrict__ bw,
                                                      const float* __restrict__ sw,
                                                      const float* __restrict__ sc,
                                                      unsigned short* __restrict__ wpk) {
    int total = NLAYER * 9 * 4 * 8 * 64 * 8;
    for (int idx = blockIdx.x * blockDim.x + threadIdx.x; idx < total; idx += gridDim.x * blockDim.x) {
        int e    = idx & 7;
        int lane = (idx >> 3) & 63;
        int cf   = (idx >> 9) & 7;
        int kk   = (idx >> 12) & 3;
        int cc   = (idx >> 14) % 9;
        int l    = idx / (9 << 14);
        int o = cf * 16 + (lane & 15);
        int k = kk * 32 + ((lane >> 4) << 3) + e;
        float v;
        if (cc == 8) {                 // silu chunk
            v = bw[(l * 128 + o) * 128 + k];
        } else {                       // spline chunk: 16 feats x 8 bases
            int f = cc * 16 + (k >> 3);
            int j = k & 7;
            int base = (l * 128 + o) * 128 + f;
            v = sw[base * 8 + j] * sc[base];
        }
        wpk[idx] = f2bf_rn(v);
    }
}

// out: [gcc(36)][kk(4)][cf(4)][lane(64)][e(8)], cols >= NCLS zeroed
__global__ __launch_bounds__(256) void pack_out_mfma(const float* __restrict__ bw,
                                                     const float* __restrict__ sw,
                                                     const float* __restrict__ sc,
                                                     unsigned short* __restrict__ wpk) {
    int total = 36 * 4 * 4 * 64 * 8;
    for (int idx = blockIdx.x * blockDim.x + threadIdx.x; idx < total; idx += gridDim.x * blockDim.x) {
        int e    = idx & 7;
        int lane = (idx >> 3) & 63;
        int cf   = (idx >> 9) & 3;
        int kk   = (idx >> 11) & 3;
        int gcc  = idx >> 13;
        int g = gcc / 9, cc = gcc % 9;
        int o = cf * 16 + (lane & 15);
        int k = kk * 32 + ((lane >> 4) << 3) + e;
        float v = 0.f;
        if (o < NCLS) {
            if (cc == 8) {
                int f = g * 128 + k;
                v = bw[o * DCAT + f];
            } else {
                int f = g * 128 + cc * 16 + (k >> 3);
                int j = k & 7;
                int base = o * DCAT + f;
                v = sw[base * 8 + j] * sc[base];
            }
        }
        wpk[idx] = f2bf_rn(v);
    }
}

// ---------------- misc ----------------

__global__ __launch_bounds__(512) void affine_init_kernel(float* scA, float* shA) {
    int i = threadIdx.x;
    scA[i] = 1.f; shA[i] = 0.f;
}

// ---------------- fused KAN GEMM + out-layer partial (bf16 MFMA 16x16x32) ----
// Block: 256 threads (4 waves), tile 64 nodes -> 782 blocks.
// phi double-buffered in LDS, one lgkm-only barrier/chunk; W fragments
// prefetched into regs one chunk ahead; x prefetched two chunks ahead; silu
// kept in registers (chunks 0..7) and written to LDS as chunk 8.
// phi spline row built via 128-bit funnel shift (w-quad at bit 16*(c-3)).
template<bool CONV, bool INIT>
__global__ __launch_bounds__(256, 2) void kan_fused_kernel(
    const float* __restrict__ xin, int xstride, int in_off,
    const float* __restrict__ scA, const float* __restrict__ shA,
    const unsigned short* __restrict__ wconv,
    const unsigned short* __restrict__ wout,
    unsigned short* __restrict__ htmp,
    const float* __restrict__ dinv,
    float* __restrict__ out_acc, int N) {

    __shared__ __align__(16) char lds_phi0[16384];
    __shared__ __align__(16) char lds_phi1[16384];

    const int tid = threadIdx.x;
    const int lane = tid & 63;
    const int wave = tid >> 6;
    const int l15 = lane & 15, lg = lane >> 4;
    const int nblk = blockIdx.x * 64;

    const float g0 = -1.f - 3.f * 0.4f;
    const float invh = 1.f / 0.4f;

    const int fg = tid & 3;
    const int n0 = tid >> 2;   // 0..63

    f32x4 accc[4][2];
    f32x4 acco[4];
    if (CONV) {
#pragma unroll
        for (int r = 0; r < 4; ++r)
#pragma unroll
            for (int c = 0; c < 2; ++c) accc[r][c] = (f32x4)0.f;
    }
#pragma unroll
    for (int r = 0; r < 4; ++r) acco[r] = (f32x4)0.f;

    // double-buffered x/affine (2 chunks ahead)
    float4 xqb[2], scb[2], shb[2];
    auto ldx = [&](int cc, int slot) {
        int f0 = in_off + cc * 16 + fg * 4;   // in_off==0 when xstride==F_IN
        scb[slot] = *(const float4*)(scA + f0);
        shb[slot] = *(const float4*)(shA + f0);
        int gn = nblk + n0;
        xqb[slot] = (gn < N) ? *(const float4*)(xin + (size_t)gn * xstride + f0)
                             : (float4){0.f, 0.f, 0.f, 0.f};
    };

    // W fragments for one chunk, prefetched a chunk ahead
    s16x8 wc_reg[4][2];
    s16x8 wo_reg[4];
    auto loadW = [&](int cc) {
        if (CONV) {
            const unsigned short* wcb = wconv + (size_t)cc * 16384;
#pragma unroll
            for (int kk = 0; kk < 4; ++kk)
#pragma unroll
                for (int c = 0; c < 2; ++c) {
                    int cf = wave * 2 + c;
                    wc_reg[kk][c] = *(const s16x8*)(wcb + (((size_t)kk * 8 + cf) * 64 + lane) * 8);
                }
        }
        const unsigned short* wob = wout + (size_t)cc * 8192;
#pragma unroll
        for (int kk = 0; kk < 4; ++kk)
            wo_reg[kk] = *(const s16x8*)(wob + (((size_t)kk * 4 + wave) * 64 + lane) * 8);
    };

    // silu values for chunks 0..7, kept in registers (written as chunk 8)
    u16x4 sreg[8];

    // per-feature spline rows as 128-bit {lo,hi}
    u64x2 pcur[4];
    auto phi_compute = [&](int ccc, int slot) {
        float xi[4] = {xqb[slot].x, xqb[slot].y, xqb[slot].z, xqb[slot].w};
        float scr[4] = {scb[slot].x, scb[slot].y, scb[slot].z, scb[slot].w};
        float shr[4] = {shb[slot].x, shb[slot].y, shb[slot].z, shb[slot].w};
        u16x4 sv;
#pragma unroll
        for (int fl = 0; fl < 4; ++fl) {
            float y = fmaf(xi[fl], scr[fl], shr[fl]);
            sv[fl] = f2bf_rn(silu_f(y));
            float t = (y - g0) * invh;
            float cfl = floorf(t);
            int c = (int)cfl;
            c = c < -20 ? -20 : (c > 20 ? 20 : c);   // keep pos arithmetic safe
            float u = t - cfl;
            float um = 1.f - u;
            float u2 = u * u;
            float um2 = um * um;
            float w0 = um2 * um * (1.f / 6.f);
            float w3 = u2 * u * (1.f / 6.f);
            float w1 = fmaf(fmaf(0.5f, u, -1.f), u2, 2.f / 3.f);
            float w2 = fmaf(fmaf(-0.5f, u, 0.5f), u2, fmaf(0.5f, u, 1.f / 6.f));
            // pack w-quad (slot order w0..w3) into u64
            unsigned long long W = (unsigned long long)f2bf_rn(w0)
                                 | ((unsigned long long)f2bf_rn(w1) << 16)
                                 | ((unsigned long long)f2bf_rn(w2) << 32)
                                 | ((unsigned long long)f2bf_rn(w3) << 48);
            // place at bit offset 16*(c-3) within the 128-bit row
            int pos = (c - 3) * 16;
            unsigned long long lo = (pos >= 0) ? (W << (pos & 63)) : (W >> ((-pos) & 63));
            lo = (pos >= 64 || pos <= -64) ? 0ull : lo;
            int ph = pos - 64;
            unsigned long long hi = (ph >= 0) ? (W << (ph & 63)) : (W >> ((-ph) & 63));
            hi = (ph >= 64 || ph <= -64) ? 0ull : hi;
            u64x2 v; v.x = lo; v.y = hi;
            pcur[fl] = v;
        }
        sreg[ccc] = sv;
    };

    auto write_phi = [&](char* buf) {
        int swz = (n0 & 7) << 4;
#pragma unroll
        for (int i = 0; i < 4; ++i) {
            int byte = n0 * 256 + ((fg * 64 + i * 16) ^ swz);
            *(u64x2*)(buf + byte) = pcur[i];
        }
    };

    auto write_silu = [&](char* buf) {
        int swz = (n0 & 7) << 4;
#pragma unroll
        for (int ccc = 0; ccc < 8; ++ccc) {
            int byte = n0 * 256 + (((ccc * 16 + fg * 4) * 2) ^ swz);
            *(u16x4*)(buf + byte) = sreg[ccc];
        }
    };

    auto mfma_phase = [&](const char* buf) {
#pragma unroll
        for (int kk = 0; kk < 4; ++kk) {
            const int kb = kk * 64 + lg * 16;
            s16x8 af[4];
#pragma unroll
            for (int r = 0; r < 4; ++r) {
                int n = r * 16 + l15;
                af[r] = *(const s16x8*)(buf + n * 256 + (kb ^ ((n & 7) << 4)));
            }
            if (CONV) {
#pragma unroll
                for (int c = 0; c < 2; ++c)
#pragma unroll
                    for (int r = 0; r < 4; ++r)
                        accc[r][c] = __builtin_amdgcn_mfma_f32_16x16x32_bf16(af[r], wc_reg[kk][c], accc[r][c], 0, 0, 0);
            }
#pragma unroll
            for (int r = 0; r < 4; ++r)
                acco[r] = __builtin_amdgcn_mfma_f32_16x16x32_bf16(af[r], wo_reg[kk], acco[r], 0, 0, 0);
        }
    };

    // ---- prologue: chunk 0 phi + W(0) + x(1) prefetch ----
    ldx(0, 0);
    phi_compute(0, 0);
    ldx(1, 1);
    loadW(0);
    write_phi(lds_phi0);
    __syncthreads();   // full drain once

    // ---- pipelined chunk loop (fully unrolled; one lgkm-barrier per chunk) ----
#pragma unroll
    for (int cc = 0; cc < 9; ++cc) {
        char* cur = (cc & 1) ? lds_phi1 : lds_phi0;
        char* nxt = (cc & 1) ? lds_phi0 : lds_phi1;
        if (cc < 7) ldx(cc + 2, cc & 1);       // issue x early (covered by MFMA+phi)
        mfma_phase(cur);
        if (cc < 8) loadW(cc + 1);             // prefetch next chunk's W
        if (cc < 7) {
            phi_compute(cc + 1, (cc + 1) & 1); // overlaps W-load latency
            write_phi(nxt);
        }
        if (cc == 7) write_silu(nxt);          // chunk 8 = silu from registers
        if (cc < 8) lds_barrier();             // ds-drain only; globals stay in flight
    }

    // epilogue: C row = r*16 + lg*4 + q, conv col = wave*32 + c*16 + l15, out col = wave*16 + l15
#pragma unroll
    for (int r = 0; r < 4; ++r) {
        int nb = nblk + r * 16 + lg * 4;
        if (CONV) {
#pragma unroll
            for (int c = 0; c < 2; ++c) {
                int o = wave * 32 + c * 16 + l15;
#pragma unroll
                for (int q = 0; q < 4; ++q) {
                    int n = nb + q;
                    if (n < N) htmp[(size_t)n * HID + o] = f2bf_rn(accc[r][c][q] * dinv[n]);
                }
            }
        }
        {
            int o = wave * 16 + l15;
            if (o < NCLS) {
#pragma unroll
                for (int q = 0; q < 4; ++q) {
                    int n = nb + q;
                    if (n < N) {
                        size_t a = (size_t)n * OOUT + o;
                        float v = acco[r][q];
                        if (!INIT) v += out_acc[a];
                        out_acc[a] = v;
                    }
                }
            }
        }
    }
}

// ---------------- aggregation (wave per node, 4 rows per memory instr) -------
// Lane = (edge-group eg = lane>>4) x (col-group cg = lane&15, 8 cols each).
// csr loaded once per 64 edges, redistributed by shfl; 16 rows in flight via
// 4 straight-line guarded iterations; shfl_xor finish across edge groups.
__global__ __launch_bounds__(256) void agg_kernel(const unsigned short* __restrict__ h,
                                                  const float* __restrict__ dinv,
                                                  const int* __restrict__ offs,
                                                  const int* __restrict__ csr,
                                                  const float* __restrict__ bias,
                                                  float* __restrict__ xc, int out_off, int N) {
    int n = blockIdx.x * 4 + (threadIdx.x >> 6);
    if (n >= N) return;
    int lane = threadIdx.x & 63;
    int eg = lane >> 4;        // 0..3
    int cg = lane & 15;        // col group: cols cg*8..cg*8+7
    int s = offs[n], e = offs[n + 1];

    float acc[4][8];
#pragma unroll
    for (int a = 0; a < 4; ++a)
#pragma unroll
        for (int k = 0; k < 8; ++k) acc[a][k] = 0.f;

    for (int base = s; base < e; base += 64) {
        int cnt = e - base; if (cnt > 64) cnt = 64;
        int ci = base + lane;
        int cv = (ci < e) ? csr[ci] : 0;

#pragma unroll
        for (int j = 0; j < 4; ++j) {
            int ei = j * 4 + eg;
            int v = __shfl(cv, ei);
            if (ei < cnt) {
                u16x8 hv = *(const u16x8*)(h + (size_t)v * HID + cg * 8);
#pragma unroll
                for (int k = 0; k < 8; ++k) acc[j][k] += bf2f(hv[k]);
            }
        }
        int nj = (cnt + 3) >> 2;
        for (int j = 4; j < nj; ++j) {
            int ei = j * 4 + eg;
            int v = __shfl(cv, ei);
            if (ei < cnt) {
                u16x8 hv = *(const u16x8*)(h + (size_t)v * HID + cg * 8);
#pragma unroll
                for (int k = 0; k < 8; ++k) acc[j & 3][k] += bf2f(hv[k]);
            }
        }
    }

    float tot[8];
#pragma unroll
    for (int k = 0; k < 8; ++k)
        tot[k] = (acc[0][k] + acc[1][k]) + (acc[2][k] + acc[3][k]);
#pragma unroll
    for (int k = 0; k < 8; ++k) {
        tot[k] += __shfl_xor(tot[k], 16);
        tot[k] += __shfl_xor(tot[k], 32);
    }
    if (eg == 0) {
        float dn = dinv[n];
        float4 b0 = *(const float4*)(bias + cg * 8);
        float4 b1 = *(const float4*)(bias + cg * 8 + 4);
        float4 o0 = {fmaf(tot[0], dn, b0.x), fmaf(tot[1], dn, b0.y),
                     fmaf(tot[2], dn, b0.z), fmaf(tot[3], dn, b0.w)};
        float4 o1 = {fmaf(tot[4], dn, b1.x), fmaf(tot[5], dn, b1.y),
                     fmaf(tot[6], dn, b1.z), fmaf(tot[7], dn, b1.w)};
        float* dst = xc + (size_t)n * DCAT + out_off + cg * 8;
        *(float4*)dst = o0;
        *(float4*)(dst + 4) = o1;
    }
}

// ---------------- batchnorm stats + deferred affine ----------------
__global__ __launch_bounds__(128) void bn_stats_kernel(const float* __restrict__ xc, int off, int N,
                                                       float* __restrict__ bnsum, float* __restrict__ bnsq) {
    int f = threadIdx.x;
    float s = 0.f, q = 0.f;
    for (int n = blockIdx.x; n < N; n += gridDim.x) {
        float v = xc[(size_t)n * DCAT + off + f];
        s += v;
        q += v * v;
    }
    atomicAdd(&bnsum[f], s);
    atomicAdd(&bnsq[f], q);
}

__global__ __launch_bounds__(128) void bn_affine_kernel(const float* __restrict__ bnsum,
                                                        const float* __restrict__ bnsq,
                                                        const float* __restrict__ gamma,
                                                        const float* __restrict__ beta,
                                                        float* scA, float* shA, int seg_off, float invN) {
    int f = threadIdx.x;
    float mu = bnsum[f] * invN;
    float var = bnsq[f] * invN - mu * mu;
    float rs = rsqrtf(var + 1e-5f);
    float s = gamma[f] * rs;
    scA[seg_off + f] = s;
    shA[seg_off + f] = fmaf(-mu, s, beta[f]);
}

// ---------------- log_softmax (thread per node; reads out_acc ld=64) ---------
__global__ __launch_bounds__(256) void logsoftmax_kernel(const float* __restrict__ oacc,
                                                         float* __restrict__ out, int N) {
    for (int n = blockIdx.x * blockDim.x + threadIdx.x; n < N; n += gridDim.x * blockDim.x) {
        const float* row = oacc + (size_t)n * OOUT;
        float m = -1e30f;
#pragma unroll
        for (int j = 0; j < NCLS; ++j) m = fmaxf(m, row[j]);
        float s = 0.f;
#pragma unroll
        for (int j = 0; j < NCLS; ++j) s += __expf(row[j] - m);
        float lse = m + __logf(s);
        float* orow = out + (size_t)n * NCLS;
#pragma unroll
        for (int j = 0; j < NCLS; ++j) orow[j] = row[j] - lse;
    }
}

// ---------------- launch ----------------

extern "C" void kernel_launch(void* const* d_in, const int* in_sizes, int n_in,
                              void* d_out, int out_size, void* d_ws, size_t ws_size,
                              hipStream_t stream) {
    const float* x            = (const float*)d_in[0];
    const int*   eidx         = (const int*)d_in[1];
    const float* conv_base_w  = (const float*)d_in[3];
    const float* conv_spline_w= (const float*)d_in[4];
    const float* conv_scaler  = (const float*)d_in[5];
    const float* conv_bias    = (const float*)d_in[6];
    const float* bn_gamma     = (const float*)d_in[7];
    const float* bn_beta      = (const float*)d_in[8];
    const float* out_base_w   = (const float*)d_in[10];
    const float* out_spline_w = (const float*)d_in[11];
    const float* out_scaler   = (const float*)d_in[12];
    float* out = (float*)d_out;

    int N = in_sizes[0] / F_IN;
    int E = in_sizes[1] / 2;
    const int* esrc = eidx;
    const int* edst = eidx + E;

    int blocks = (N + 63) / 64;
    int npad = blocks * 64;
    int nsb = (N + 255) / 256;

    char* p = (char*)d_ws;
    auto carve = [&](size_t bytes) {
        char* r = p;
        p += (bytes + 255) & ~(size_t)255;
        return r;
    };
    float* xc   = (float*)carve((size_t)N * DCAT * 4);
    unsigned short* htmp = (unsigned short*)carve((size_t)npad * HID * 2);
    float* oacc = (float*)carve((size_t)npad * OOUT * 4);
    float* dinv = (float*)carve((size_t)N * 4);
    float* bn   = (float*)carve((size_t)NLAYER * 2 * HID * 4);
    float* scA  = (float*)carve((size_t)DCAT * 4);
    float* shA  = (float*)carve((size_t)DCAT * 4);
    unsigned short* wpkc = (unsigned short*)carve((size_t)NLAYER * 9 * 128 * 128 * 2);
    unsigned short* wpko = (unsigned short*)carve((size_t)36 * 64 * 128 * 2);
    int* deg    = (int*)carve((size_t)N * 4);
    int* offs   = (int*)carve((size_t)(N + 1) * 4);
    int* cursor = (int*)carve((size_t)(N + 1) * 4);
    int* bsum   = (int*)carve((size_t)nsb * 4);
    int* bbase  = (int*)carve((size_t)nsb * 4);
    int* csr    = (int*)carve((size_t)(E + N) * 4);

    hipMemsetAsync(bn, 0, NLAYER * 2 * HID * 4, stream);

    // graph preprocessing
    deg_init_kernel<<<512, 256, 0, stream>>>(deg, N);
    deg_count_kernel<<<1024, 256, 0, stream>>>(edst, E, deg);
    dinv_kernel<<<512, 256, 0, stream>>>(deg, dinv, N);
    scan_reduce_kernel<<<nsb, 256, 0, stream>>>(deg, bsum, N);
    scan_top_kernel<<<1, 256, 0, stream>>>(bsum, bbase, nsb);
    scan_write_kernel<<<nsb, 256, 0, stream>>>(deg, bbase, offs, cursor, N);
    fill_kernel<<<1024, 256, 0, stream>>>(esrc, edst, E, N, cursor, csr);

    // weight packing + affine init
    pack_conv_mfma<<<1024, 256, 0, stream>>>(conv_base_w, conv_spline_w, conv_scaler, wpkc);
    pack_out_mfma<<<1024, 256, 0, stream>>>(out_base_w, out_spline_w, out_scaler, wpko);
    affine_init_kernel<<<1, 512, 0, stream>>>(scA, shA);

    float invN = 1.f / (float)N;
    for (int l = 0; l < NLAYER; ++l) {
        int in_off = l * HID;
        int out_off = (l + 1) * HID;
        const unsigned short* wl = wpkc + (size_t)l * 9 * 16384;
        const unsigned short* wo = wpko + (size_t)l * 9 * 8192;
        if (l == 0)
            kan_fused_kernel<true, true><<<blocks, 256, 0, stream>>>(
                x, F_IN, 0, scA, shA, wl, wo, htmp, dinv, oacc, N);
        else
            kan_fused_kernel<true, false><<<blocks, 256, 0, stream>>>(
                xc, DCAT, in_off, scA, shA, wl, wo, htmp, dinv, oacc, N);
        agg_kernel<<<(N + 3) / 4, 256, 0, stream>>>(htmp, dinv, offs, csr, conv_bias + l * HID, xc, out_off, N);
        float* bnsum = bn + l * 2 * HID;
        float* bnsq  = bnsum + HID;
        bn_stats_kernel<<<256, 128, 0, stream>>>(xc, out_off, N, bnsum, bnsq);
        bn_affine_kernel<<<1, 128, 0, stream>>>(bnsum, bnsq, bn_gamma + l * HID, bn_beta + l * HID,
                                                scA, shA, out_off, invN);
    }

    // segment 3 (final BN output) -> out partial
    kan_fused_kernel<false, false><<<blocks, 256, 0, stream>>>(
        xc, DCAT, 384, scA, shA, nullptr, wpko + (size_t)3 * 9 * 8192, htmp, dinv, oacc, N);

    logsoftmax_kernel<<<(N + 255) / 256, 256, 0, stream>>>(oacc, out, N);
}